// Round 4
// baseline (944.243 us; speedup 1.0000x reference)
//
#include <hip/hip_runtime.h>
#include <math.h>

#define N_NODES 100000
#define F_IN    100
#define HIDDEN  16
#define N_CLASS 18

#define BKT_SHIFT 7
#define BKT_NODES 128                                   // nodes per bucket
#define NBKT ((N_NODES + BKT_NODES - 1) / BKT_NODES)    // 782
#define TILE 8192                                       // edges per k_bucket block

// ---- edge dtype detector: int64 little-endian (values < 2^31) has all-zero odd int32 words
__global__ void k_detect(const int* __restrict__ ei, int* __restrict__ flag) {
    int z = 1;
    for (int i = 0; i < 16; ++i) {
        if (ei[2 * i + 1] != 0) z = 0;
    }
    *flag = z;  // 1 => int64 layout, 0 => int32 layout
}

__device__ __forceinline__ int edge_at(const int* __restrict__ ei, long long idx, int is64) {
    return is64 ? ei[2 * idx] : ei[idx];
}

// ---- per-node in-degree histogram (for dinv and bucket counts)
__global__ __launch_bounds__(256) void k_hist(const int* __restrict__ ei, long long E,
                                              const int* __restrict__ flag,
                                              int* __restrict__ cnt) {
    long long e = (long long)blockIdx.x * 256 + threadIdx.x;
    if (e >= E) return;
    int is64 = *flag;
    int d = edge_at(ei, E + e, is64);
    atomicAdd(&cnt[d], 1);
}

__global__ __launch_bounds__(256) void k_dinv(const int* __restrict__ cnt,
                                              float* __restrict__ dinv) {
    int i = blockIdx.x * 256 + threadIdx.x;
    if (i < N_NODES) dinv[i] = rsqrtf((float)cnt[i] + 1.0f);
}

// ---- bucket totals from per-node counts
__global__ __launch_bounds__(256) void k_bktcnt(const int* __restrict__ cnt,
                                                int* __restrict__ bcnt) {
    int b = blockIdx.x * 256 + threadIdx.x;
    if (b >= NBKT) return;
    int n0 = b * BKT_NODES;
    int n1 = min(n0 + BKT_NODES, N_NODES);
    int s = 0;
    for (int n = n0; n < n1; ++n) s += cnt[n];
    bcnt[b] = s;
}

// ---- single-block scan over 782 bucket counts -> bases + global cursors
__global__ __launch_bounds__(1024) void k_bktscan(const int* __restrict__ bcnt,
                                                  int* __restrict__ gcur,
                                                  int* __restrict__ bkt_base) {
    __shared__ int s[1024];
    int tid = threadIdx.x;
    int v = (tid < NBKT) ? bcnt[tid] : 0;
    s[tid] = v;
    __syncthreads();
    for (int off = 1; off < 1024; off <<= 1) {
        int t = (tid >= off) ? s[tid - off] : 0;
        __syncthreads();
        s[tid] += t;
        __syncthreads();
    }
    if (tid < NBKT) {
        int e = s[tid] - v;  // exclusive
        gcur[tid] = e;
        bkt_base[tid] = e;
    }
    if (tid == 1023) bkt_base[NBKT] = s[1023];
}

// ---- level-1 split: per-tile LDS counting sort by bucket, coalesced packed writes
// pairs[pos] = src | (dst&127)<<17   (src < 2^17, dst-local 7 bits)
__global__ __launch_bounds__(256) void k_bucket(const int* __restrict__ ei, long long E,
                                                const int* __restrict__ flag,
                                                int* __restrict__ gcur,
                                                int* __restrict__ pairs) {
    __shared__ int hist[NBKT];
    __shared__ int lbase[NBKT];
    __shared__ int gbase[NBKT];
    __shared__ int lcur[NBKT];
    __shared__ unsigned short perm[TILE];
    __shared__ int ts[256];
    int tid = threadIdx.x;
    int is64 = *flag;
    long long e0 = (long long)blockIdx.x * TILE;
    int n = (int)(((E - e0) < (long long)TILE) ? (E - e0) : (long long)TILE);

    for (int i = tid; i < NBKT; i += 256) hist[i] = 0;
    __syncthreads();
    for (int i = tid; i < n; i += 256) {
        int d = edge_at(ei, E + e0 + i, is64);
        atomicAdd(&hist[d >> BKT_SHIFT], 1);
    }
    __syncthreads();

    // exclusive scan of hist into lbase; thread owns 4 consecutive buckets
    int b0 = tid * 4;
    int h0 = (b0 + 0 < NBKT) ? hist[b0 + 0] : 0;
    int h1 = (b0 + 1 < NBKT) ? hist[b0 + 1] : 0;
    int h2 = (b0 + 2 < NBKT) ? hist[b0 + 2] : 0;
    int h3 = (b0 + 3 < NBKT) ? hist[b0 + 3] : 0;
    int tsum = h0 + h1 + h2 + h3;
    ts[tid] = tsum;
    __syncthreads();
    for (int off = 1; off < 256; off <<= 1) {
        int t = (tid >= off) ? ts[tid - off] : 0;
        __syncthreads();
        ts[tid] += t;
        __syncthreads();
    }
    int eb = ts[tid] - tsum;
    if (b0 + 0 < NBKT) lbase[b0 + 0] = eb;
    if (b0 + 1 < NBKT) lbase[b0 + 1] = eb + h0;
    if (b0 + 2 < NBKT) lbase[b0 + 2] = eb + h0 + h1;
    if (b0 + 3 < NBKT) lbase[b0 + 3] = eb + h0 + h1 + h2;

    // reserve this block's run in each bucket's global region
    for (int b = tid; b < NBKT; b += 256) {
        int c = hist[b];
        gbase[b] = (c > 0) ? atomicAdd(&gcur[b], c) : 0;
    }
    __syncthreads();
    for (int i = tid; i < NBKT; i += 256) lcur[i] = lbase[i];
    __syncthreads();

    // local binning (perm holds tile-local edge ids, grouped by bucket)
    for (int i = tid; i < n; i += 256) {
        int d = edge_at(ei, E + e0 + i, is64);
        int l = atomicAdd(&lcur[d >> BKT_SHIFT], 1);
        perm[l] = (unsigned short)i;
    }
    __syncthreads();

    // write out: consecutive k within a bucket-run -> consecutive positions
    for (int k = tid; k < n; k += 256) {
        int i = perm[k];
        int s = edge_at(ei, e0 + i, is64);
        int d = edge_at(ei, E + e0 + i, is64);
        int b = d >> BKT_SHIFT;
        int pos = gbase[b] + (k - lbase[b]);
        pairs[pos] = s | ((d & (BKT_NODES - 1)) << 17);
    }
}

// ---- h = relu(x @ W1 + b1)   [N,100]@[100,16]
__global__ __launch_bounds__(256) void k_lin1(const float* __restrict__ x,
                                              const float* __restrict__ W1,
                                              const float* __restrict__ b1,
                                              float* __restrict__ h) {
    __shared__ float sW[F_IN * HIDDEN];
    __shared__ float sb[HIDDEN];
    for (int i = threadIdx.x; i < F_IN * HIDDEN; i += 256) sW[i] = W1[i];
    if (threadIdx.x < HIDDEN) sb[threadIdx.x] = b1[threadIdx.x];
    __syncthreads();
    int node = blockIdx.x * 256 + threadIdx.x;
    if (node >= N_NODES) return;

    float acc[HIDDEN];
#pragma unroll
    for (int j = 0; j < HIDDEN; ++j) acc[j] = sb[j];

    const float4* x4 = reinterpret_cast<const float4*>(x + (long long)node * F_IN);
#pragma unroll 2
    for (int k4 = 0; k4 < F_IN / 4; ++k4) {
        float4 xv = x4[k4];
        const float* w = &sW[k4 * 4 * HIDDEN];
#pragma unroll
        for (int j = 0; j < HIDDEN; ++j) {
            acc[j] += xv.x * w[0 * HIDDEN + j];
            acc[j] += xv.y * w[1 * HIDDEN + j];
            acc[j] += xv.z * w[2 * HIDDEN + j];
            acc[j] += xv.w * w[3 * HIDDEN + j];
        }
    }
    float4* hr = reinterpret_cast<float4*>(h + (long long)node * HIDDEN);
#pragma unroll
    for (int q = 0; q < HIDDEN / 4; ++q) {
        float4 o;
        o.x = fmaxf(acc[q * 4 + 0], 0.0f);
        o.y = fmaxf(acc[q * 4 + 1], 0.0f);
        o.z = fmaxf(acc[q * 4 + 2], 0.0f);
        o.w = fmaxf(acc[q * 4 + 3], 0.0f);
        hr[q] = o;
    }
}

// ---- tmp' = dinv[i] * (h @ W)
__global__ __launch_bounds__(256) void k_mm16(const float* __restrict__ h,
                                              const float* __restrict__ W,
                                              const float* __restrict__ dinv,
                                              float* __restrict__ tmpp) {
    __shared__ float sW[HIDDEN * HIDDEN];
    if (threadIdx.x < HIDDEN * HIDDEN) sW[threadIdx.x] = W[threadIdx.x];
    __syncthreads();
    int node = blockIdx.x * 256 + threadIdx.x;
    if (node >= N_NODES) return;

    float hv[HIDDEN];
    const float4* hr = reinterpret_cast<const float4*>(h + (long long)node * HIDDEN);
#pragma unroll
    for (int q = 0; q < HIDDEN / 4; ++q) {
        float4 v = hr[q];
        hv[q * 4 + 0] = v.x; hv[q * 4 + 1] = v.y;
        hv[q * 4 + 2] = v.z; hv[q * 4 + 3] = v.w;
    }
    float di = dinv[node];
    float out[HIDDEN];
#pragma unroll
    for (int j = 0; j < HIDDEN; ++j) out[j] = 0.0f;
#pragma unroll
    for (int k = 0; k < HIDDEN; ++k) {
        float hk = hv[k];
#pragma unroll
        for (int j = 0; j < HIDDEN; ++j) out[j] += hk * sW[k * HIDDEN + j];
    }
    float4* tp = reinterpret_cast<float4*>(tmpp + (long long)node * HIDDEN);
#pragma unroll
    for (int q = 0; q < HIDDEN / 4; ++q) {
        float4 o;
        o.x = di * out[q * 4 + 0];
        o.y = di * out[q * 4 + 1];
        o.z = di * out[q * 4 + 2];
        o.w = di * out[q * 4 + 3];
        tp[q] = o;
    }
}

// ---- per-bucket aggregation in LDS, MLP-16 inner loop, fused epilogue
// h[n] = relu(dinv[n]*(sum_src tmpp[src] + tmpp[n]) + b)
__global__ __launch_bounds__(512) void k_aggr(const int* __restrict__ bkt_base,
                                              const int* __restrict__ pairs,
                                              const float* __restrict__ tmpp,
                                              const float* __restrict__ dinv,
                                              const float* __restrict__ b,
                                              float* __restrict__ h) {
    __shared__ float agg[BKT_NODES * HIDDEN];  // 8 KB
    int tid = threadIdx.x;
    int bk = blockIdx.x;
    for (int i = tid; i < BKT_NODES * HIDDEN; i += 512) agg[i] = 0.0f;
    __syncthreads();
    int i0 = bkt_base[bk], i1 = bkt_base[bk + 1];
    int f  = tid & 15;
    int g  = tid >> 4;          // 0..31 groups of 16 lanes
    int gw = g & 3;             // group index within the 64-lane wave

    for (int base = i0 + g * 16; base < i1; base += 32 * 16) {
        int idx = base + f;
        int v = (idx < i1) ? pairs[idx] : -1;   // coalesced 64-B line per group
        int   vjs[16];
        float vals[16];
        // phase 1: broadcast each edge, issue all 16 independent gathers
#pragma unroll
        for (int j = 0; j < 16; ++j) {
            int vj = __shfl(v, gw * 16 + j);
            vjs[j] = vj;
            vals[j] = (vj >= 0) ? tmpp[(long long)(vj & 0x1FFFF) * HIDDEN + f] : 0.0f;
        }
        // phase 2: accumulate into LDS
#pragma unroll
        for (int j = 0; j < 16; ++j) {
            if (vjs[j] >= 0)
                atomicAdd(&agg[(vjs[j] >> 17) * HIDDEN + f], vals[j]);
        }
    }
    __syncthreads();
    int nb = bk * BKT_NODES;
    for (int i = tid; i < BKT_NODES * HIDDEN; i += 512) {
        int dl = i >> 4, ff = i & 15;
        int node = nb + dl;
        if (node < N_NODES) {
            float val = dinv[node] * (agg[i] + tmpp[(long long)node * HIDDEN + ff]) + b[ff];
            h[(long long)node * HIDDEN + ff] = fmaxf(val, 0.0f);
        }
    }
}

// ---- out = log_softmax(h @ W2 + b2)
__global__ __launch_bounds__(256) void k_out(const float* __restrict__ h,
                                             const float* __restrict__ W2,
                                             const float* __restrict__ b2,
                                             float* __restrict__ out) {
    __shared__ float sW[HIDDEN * N_CLASS];
    __shared__ float sb[N_CLASS];
    for (int i = threadIdx.x; i < HIDDEN * N_CLASS; i += 256) sW[i] = W2[i];
    if (threadIdx.x < N_CLASS) sb[threadIdx.x] = b2[threadIdx.x];
    __syncthreads();
    int node = blockIdx.x * 256 + threadIdx.x;
    if (node >= N_NODES) return;

    float hv[HIDDEN];
    const float4* hr = reinterpret_cast<const float4*>(h + (long long)node * HIDDEN);
#pragma unroll
    for (int q = 0; q < HIDDEN / 4; ++q) {
        float4 v = hr[q];
        hv[q * 4 + 0] = v.x; hv[q * 4 + 1] = v.y;
        hv[q * 4 + 2] = v.z; hv[q * 4 + 3] = v.w;
    }
    float z[N_CLASS];
#pragma unroll
    for (int c = 0; c < N_CLASS; ++c) z[c] = sb[c];
#pragma unroll
    for (int k = 0; k < HIDDEN; ++k) {
        float hk = hv[k];
#pragma unroll
        for (int c = 0; c < N_CLASS; ++c) z[c] += hk * sW[k * N_CLASS + c];
    }
    float m = z[0];
#pragma unroll
    for (int c = 1; c < N_CLASS; ++c) m = fmaxf(m, z[c]);
    float ssum = 0.0f;
#pragma unroll
    for (int c = 0; c < N_CLASS; ++c) ssum += expf(z[c] - m);
    float l = m + logf(ssum);
    float* orow = out + (long long)node * N_CLASS;
#pragma unroll
    for (int c = 0; c < N_CLASS; ++c) orow[c] = z[c] - l;
}

static inline char* align256(char* p) {
    return (char*)(((size_t)p + 255) & ~(size_t)255);
}

extern "C" void kernel_launch(void* const* d_in, const int* in_sizes, int n_in,
                              void* d_out, int out_size, void* d_ws, size_t ws_size,
                              hipStream_t stream) {
    const float* x   = (const float*)d_in[0];
    const int*   ei  = (const int*)d_in[1];
    const float* W1  = (const float*)d_in[2];
    const float* b1  = (const float*)d_in[3];
    const float* Wc0 = (const float*)d_in[4];
    const float* bc0 = (const float*)d_in[5];
    const float* Wc1 = (const float*)d_in[6];
    const float* bc1 = (const float*)d_in[7];
    const float* W2  = (const float*)d_in[8];
    const float* b2  = (const float*)d_in[9];
    float* out = (float*)d_out;

    long long E = (long long)in_sizes[1] / 2;

    char* p = (char*)d_ws;
    int* flag      = (int*)p;            p = align256(p + sizeof(int));
    int* cnt       = (int*)p;            p = align256(p + sizeof(int) * N_NODES);
    float* dinv    = (float*)p;          p = align256(p + sizeof(float) * N_NODES);
    int* bcnt      = (int*)p;            p = align256(p + sizeof(int) * NBKT);
    int* bkt_base  = (int*)p;            p = align256(p + sizeof(int) * (NBKT + 1));
    int* gcur      = (int*)p;            p = align256(p + sizeof(int) * NBKT);
    int* pairs     = (int*)p;            p = align256(p + sizeof(int) * E);
    float* h       = (float*)p;          p = align256(p + sizeof(float) * (size_t)N_NODES * HIDDEN);
    float* tmpp    = (float*)p;          p = align256(p + sizeof(float) * (size_t)N_NODES * HIDDEN);

    const int nblk_node   = (N_NODES + 255) / 256;
    const int nblk_edge   = (int)((E + 255) / 256);
    const int nblk_bucket = (int)((E + TILE - 1) / TILE);
    const int nblk_bcnt   = (NBKT + 255) / 256;

    hipMemsetAsync(cnt, 0, sizeof(int) * N_NODES, stream);
    k_detect<<<1, 1, 0, stream>>>(ei, flag);
    k_hist<<<nblk_edge, 256, 0, stream>>>(ei, E, flag, cnt);
    k_dinv<<<nblk_node, 256, 0, stream>>>(cnt, dinv);

    k_bktcnt<<<nblk_bcnt, 256, 0, stream>>>(cnt, bcnt);
    k_bktscan<<<1, 1024, 0, stream>>>(bcnt, gcur, bkt_base);
    k_bucket<<<nblk_bucket, 256, 0, stream>>>(ei, E, flag, gcur, pairs);

    k_lin1<<<nblk_node, 256, 0, stream>>>(x, W1, b1, h);

    // conv 1
    k_mm16<<<nblk_node, 256, 0, stream>>>(h, Wc0, dinv, tmpp);
    k_aggr<<<NBKT, 512, 0, stream>>>(bkt_base, pairs, tmpp, dinv, bc0, h);

    // conv 2
    k_mm16<<<nblk_node, 256, 0, stream>>>(h, Wc1, dinv, tmpp);
    k_aggr<<<NBKT, 512, 0, stream>>>(bkt_base, pairs, tmpp, dinv, bc1, h);

    k_out<<<nblk_node, 256, 0, stream>>>(h, W2, b2, out);
}

// Round 5
// 916.000 us; speedup vs baseline: 1.0308x; 1.0308x over previous
//
#include <hip/hip_runtime.h>
#include <math.h>

#define N_NODES 100000
#define F_IN    100
#define HIDDEN  16
#define N_CLASS 18

#define BKT_SHIFT 7
#define BKT_NODES 128                                   // nodes per bucket
#define NBKT ((N_NODES + BKT_NODES - 1) / BKT_NODES)    // 782
#define TILE 8192                                       // edges per k_bucket block
#define AGG_PAD 17                                      // padded LDS row stride (banks)

// ---- edge dtype detector: int64 little-endian (values < 2^31) has all-zero odd int32 words
__global__ void k_detect(const int* __restrict__ ei, int* __restrict__ flag) {
    int z = 1;
    for (int i = 0; i < 16; ++i) {
        if (ei[2 * i + 1] != 0) z = 0;
    }
    *flag = z;  // 1 => int64 layout, 0 => int32 layout
}

__device__ __forceinline__ int edge_at(const int* __restrict__ ei, long long idx, int is64) {
    return is64 ? ei[2 * idx] : ei[idx];
}

// ---- per-node in-degree histogram (for dinv and bucket counts)
__global__ __launch_bounds__(256) void k_hist(const int* __restrict__ ei, long long E,
                                              const int* __restrict__ flag,
                                              int* __restrict__ cnt) {
    long long e = (long long)blockIdx.x * 256 + threadIdx.x;
    if (e >= E) return;
    int is64 = *flag;
    int d = edge_at(ei, E + e, is64);
    atomicAdd(&cnt[d], 1);
}

__global__ __launch_bounds__(256) void k_dinv(const int* __restrict__ cnt,
                                              float* __restrict__ dinv) {
    int i = blockIdx.x * 256 + threadIdx.x;
    if (i < N_NODES) dinv[i] = rsqrtf((float)cnt[i] + 1.0f);
}

// ---- bucket totals from per-node counts
__global__ __launch_bounds__(256) void k_bktcnt(const int* __restrict__ cnt,
                                                int* __restrict__ bcnt) {
    int b = blockIdx.x * 256 + threadIdx.x;
    if (b >= NBKT) return;
    int n0 = b * BKT_NODES;
    int n1 = min(n0 + BKT_NODES, N_NODES);
    int s = 0;
    for (int n = n0; n < n1; ++n) s += cnt[n];
    bcnt[b] = s;
}

// ---- single-block scan over 782 bucket counts -> bases + global cursors
__global__ __launch_bounds__(1024) void k_bktscan(const int* __restrict__ bcnt,
                                                  int* __restrict__ gcur,
                                                  int* __restrict__ bkt_base) {
    __shared__ int s[1024];
    int tid = threadIdx.x;
    int v = (tid < NBKT) ? bcnt[tid] : 0;
    s[tid] = v;
    __syncthreads();
    for (int off = 1; off < 1024; off <<= 1) {
        int t = (tid >= off) ? s[tid - off] : 0;
        __syncthreads();
        s[tid] += t;
        __syncthreads();
    }
    if (tid < NBKT) {
        int e = s[tid] - v;  // exclusive
        gcur[tid] = e;
        bkt_base[tid] = e;
    }
    if (tid == 1023) bkt_base[NBKT] = s[1023];
}

// ---- level-1 split: per-tile LDS counting sort by bucket, coalesced packed writes
// pairs[pos] = src | (dst&127)<<17   (src < 2^17, dst-local 7 bits)
__global__ __launch_bounds__(256) void k_bucket(const int* __restrict__ ei, long long E,
                                                const int* __restrict__ flag,
                                                int* __restrict__ gcur,
                                                int* __restrict__ pairs) {
    __shared__ int hist[NBKT];
    __shared__ int lbase[NBKT];
    __shared__ int gbase[NBKT];
    __shared__ int lcur[NBKT];
    __shared__ unsigned short perm[TILE];
    __shared__ int ts[256];
    int tid = threadIdx.x;
    int is64 = *flag;
    long long e0 = (long long)blockIdx.x * TILE;
    int n = (int)(((E - e0) < (long long)TILE) ? (E - e0) : (long long)TILE);

    for (int i = tid; i < NBKT; i += 256) hist[i] = 0;
    __syncthreads();
    for (int i = tid; i < n; i += 256) {
        int d = edge_at(ei, E + e0 + i, is64);
        atomicAdd(&hist[d >> BKT_SHIFT], 1);
    }
    __syncthreads();

    // exclusive scan of hist into lbase; thread owns 4 consecutive buckets
    int b0 = tid * 4;
    int h0 = (b0 + 0 < NBKT) ? hist[b0 + 0] : 0;
    int h1 = (b0 + 1 < NBKT) ? hist[b0 + 1] : 0;
    int h2 = (b0 + 2 < NBKT) ? hist[b0 + 2] : 0;
    int h3 = (b0 + 3 < NBKT) ? hist[b0 + 3] : 0;
    int tsum = h0 + h1 + h2 + h3;
    ts[tid] = tsum;
    __syncthreads();
    for (int off = 1; off < 256; off <<= 1) {
        int t = (tid >= off) ? ts[tid - off] : 0;
        __syncthreads();
        ts[tid] += t;
        __syncthreads();
    }
    int eb = ts[tid] - tsum;
    if (b0 + 0 < NBKT) lbase[b0 + 0] = eb;
    if (b0 + 1 < NBKT) lbase[b0 + 1] = eb + h0;
    if (b0 + 2 < NBKT) lbase[b0 + 2] = eb + h0 + h1;
    if (b0 + 3 < NBKT) lbase[b0 + 3] = eb + h0 + h1 + h2;

    // reserve this block's run in each bucket's global region
    for (int b = tid; b < NBKT; b += 256) {
        int c = hist[b];
        gbase[b] = (c > 0) ? atomicAdd(&gcur[b], c) : 0;
    }
    __syncthreads();
    for (int i = tid; i < NBKT; i += 256) lcur[i] = lbase[i];
    __syncthreads();

    // local binning (perm holds tile-local edge ids, grouped by bucket)
    for (int i = tid; i < n; i += 256) {
        int d = edge_at(ei, E + e0 + i, is64);
        int l = atomicAdd(&lcur[d >> BKT_SHIFT], 1);
        perm[l] = (unsigned short)i;
    }
    __syncthreads();

    // write out: consecutive k within a bucket-run -> consecutive positions
    for (int k = tid; k < n; k += 256) {
        int i = perm[k];
        int s = edge_at(ei, e0 + i, is64);
        int d = edge_at(ei, E + e0 + i, is64);
        int b = d >> BKT_SHIFT;
        int pos = gbase[b] + (k - lbase[b]);
        pairs[pos] = s | ((d & (BKT_NODES - 1)) << 17);
    }
}

// ---- h = relu(x @ W1 + b1)   [N,100]@[100,16]
__global__ __launch_bounds__(256) void k_lin1(const float* __restrict__ x,
                                              const float* __restrict__ W1,
                                              const float* __restrict__ b1,
                                              float* __restrict__ h) {
    __shared__ float sW[F_IN * HIDDEN];
    __shared__ float sb[HIDDEN];
    for (int i = threadIdx.x; i < F_IN * HIDDEN; i += 256) sW[i] = W1[i];
    if (threadIdx.x < HIDDEN) sb[threadIdx.x] = b1[threadIdx.x];
    __syncthreads();
    int node = blockIdx.x * 256 + threadIdx.x;
    if (node >= N_NODES) return;

    float acc[HIDDEN];
#pragma unroll
    for (int j = 0; j < HIDDEN; ++j) acc[j] = sb[j];

    const float4* x4 = reinterpret_cast<const float4*>(x + (long long)node * F_IN);
#pragma unroll 2
    for (int k4 = 0; k4 < F_IN / 4; ++k4) {
        float4 xv = x4[k4];
        const float* w = &sW[k4 * 4 * HIDDEN];
#pragma unroll
        for (int j = 0; j < HIDDEN; ++j) {
            acc[j] += xv.x * w[0 * HIDDEN + j];
            acc[j] += xv.y * w[1 * HIDDEN + j];
            acc[j] += xv.z * w[2 * HIDDEN + j];
            acc[j] += xv.w * w[3 * HIDDEN + j];
        }
    }
    float4* hr = reinterpret_cast<float4*>(h + (long long)node * HIDDEN);
#pragma unroll
    for (int q = 0; q < HIDDEN / 4; ++q) {
        float4 o;
        o.x = fmaxf(acc[q * 4 + 0], 0.0f);
        o.y = fmaxf(acc[q * 4 + 1], 0.0f);
        o.z = fmaxf(acc[q * 4 + 2], 0.0f);
        o.w = fmaxf(acc[q * 4 + 3], 0.0f);
        hr[q] = o;
    }
}

// ---- tmp' = dinv[i] * (h @ W)
__global__ __launch_bounds__(256) void k_mm16(const float* __restrict__ h,
                                              const float* __restrict__ W,
                                              const float* __restrict__ dinv,
                                              float* __restrict__ tmpp) {
    __shared__ float sW[HIDDEN * HIDDEN];
    if (threadIdx.x < HIDDEN * HIDDEN) sW[threadIdx.x] = W[threadIdx.x];
    __syncthreads();
    int node = blockIdx.x * 256 + threadIdx.x;
    if (node >= N_NODES) return;

    float hv[HIDDEN];
    const float4* hr = reinterpret_cast<const float4*>(h + (long long)node * HIDDEN);
#pragma unroll
    for (int q = 0; q < HIDDEN / 4; ++q) {
        float4 v = hr[q];
        hv[q * 4 + 0] = v.x; hv[q * 4 + 1] = v.y;
        hv[q * 4 + 2] = v.z; hv[q * 4 + 3] = v.w;
    }
    float di = dinv[node];
    float out[HIDDEN];
#pragma unroll
    for (int j = 0; j < HIDDEN; ++j) out[j] = 0.0f;
#pragma unroll
    for (int k = 0; k < HIDDEN; ++k) {
        float hk = hv[k];
#pragma unroll
        for (int j = 0; j < HIDDEN; ++j) out[j] += hk * sW[k * HIDDEN + j];
    }
    float4* tp = reinterpret_cast<float4*>(tmpp + (long long)node * HIDDEN);
#pragma unroll
    for (int q = 0; q < HIDDEN / 4; ++q) {
        float4 o;
        o.x = di * out[q * 4 + 0];
        o.y = di * out[q * 4 + 1];
        o.z = di * out[q * 4 + 2];
        o.w = di * out[q * 4 + 3];
        tp[q] = o;
    }
}

// ---- per-bucket aggregation in LDS, 4-lanes-per-edge float4 gathers, fused epilogue
// h[n] = relu(dinv[n]*(sum_src tmpp[src] + tmpp[n]) + b)
__global__ __launch_bounds__(512) void k_aggr(const int* __restrict__ bkt_base,
                                              const int* __restrict__ pairs,
                                              const float* __restrict__ tmpp,
                                              const float* __restrict__ dinv,
                                              const float* __restrict__ b,
                                              float* __restrict__ h) {
    __shared__ float agg[BKT_NODES * AGG_PAD];  // 128*17*4 = 8704 B
    int tid = threadIdx.x;
    int bk = blockIdx.x;
    for (int i = tid; i < BKT_NODES * AGG_PAD; i += 512) agg[i] = 0.0f;
    __syncthreads();
    int i0 = bkt_base[bk], i1 = bkt_base[bk + 1];
    int q  = (tid & 3) * 4;     // quarter offset within a 16-float row
    int eo = tid >> 2;          // 0..127 edge slot
    const float4* t4 = reinterpret_cast<const float4*>(tmpp);

    int nfull = (i1 - i0) >> 9;   // full 512-edge chunks
    int base = i0 + eo;
    for (int c = 0; c < nfull; ++c, base += 512) {
        // phase 1: 4 independent edge words + 4 independent float4 gathers (16 lines/instr)
        int v0 = pairs[base];
        int v1 = pairs[base + 128];
        int v2 = pairs[base + 256];
        int v3 = pairs[base + 384];
        float4 a0 = t4[(v0 & 0x1FFFF) * 4 + (tid & 3)];
        float4 a1 = t4[(v1 & 0x1FFFF) * 4 + (tid & 3)];
        float4 a2 = t4[(v2 & 0x1FFFF) * 4 + (tid & 3)];
        float4 a3 = t4[(v3 & 0x1FFFF) * 4 + (tid & 3)];
        // phase 2: LDS accumulation (padded rows -> ~conflict-free)
        int d0 = (v0 >> 17) * AGG_PAD + q;
        int d1 = (v1 >> 17) * AGG_PAD + q;
        int d2 = (v2 >> 17) * AGG_PAD + q;
        int d3 = (v3 >> 17) * AGG_PAD + q;
        atomicAdd(&agg[d0 + 0], a0.x); atomicAdd(&agg[d0 + 1], a0.y);
        atomicAdd(&agg[d0 + 2], a0.z); atomicAdd(&agg[d0 + 3], a0.w);
        atomicAdd(&agg[d1 + 0], a1.x); atomicAdd(&agg[d1 + 1], a1.y);
        atomicAdd(&agg[d1 + 2], a1.z); atomicAdd(&agg[d1 + 3], a1.w);
        atomicAdd(&agg[d2 + 0], a2.x); atomicAdd(&agg[d2 + 1], a2.y);
        atomicAdd(&agg[d2 + 2], a2.z); atomicAdd(&agg[d2 + 3], a2.w);
        atomicAdd(&agg[d3 + 0], a3.x); atomicAdd(&agg[d3 + 1], a3.y);
        atomicAdd(&agg[d3 + 2], a3.z); atomicAdd(&agg[d3 + 3], a3.w);
    }
    // tail
    for (int e = i0 + (nfull << 9) + eo; e < i1; e += 128) {
        int v = pairs[e];
        float4 a = t4[(v & 0x1FFFF) * 4 + (tid & 3)];
        int d = (v >> 17) * AGG_PAD + q;
        atomicAdd(&agg[d + 0], a.x); atomicAdd(&agg[d + 1], a.y);
        atomicAdd(&agg[d + 2], a.z); atomicAdd(&agg[d + 3], a.w);
    }
    __syncthreads();
    int nb = bk * BKT_NODES;
    for (int i = tid; i < BKT_NODES * HIDDEN; i += 512) {
        int dl = i >> 4, ff = i & 15;
        int node = nb + dl;
        if (node < N_NODES) {
            float val = dinv[node] * (agg[dl * AGG_PAD + ff] + tmpp[(long long)node * HIDDEN + ff]) + b[ff];
            h[(long long)node * HIDDEN + ff] = fmaxf(val, 0.0f);
        }
    }
}

// ---- out = log_softmax(h @ W2 + b2)
__global__ __launch_bounds__(256) void k_out(const float* __restrict__ h,
                                             const float* __restrict__ W2,
                                             const float* __restrict__ b2,
                                             float* __restrict__ out) {
    __shared__ float sW[HIDDEN * N_CLASS];
    __shared__ float sb[N_CLASS];
    for (int i = threadIdx.x; i < HIDDEN * N_CLASS; i += 256) sW[i] = W2[i];
    if (threadIdx.x < N_CLASS) sb[threadIdx.x] = b2[threadIdx.x];
    __syncthreads();
    int node = blockIdx.x * 256 + threadIdx.x;
    if (node >= N_NODES) return;

    float hv[HIDDEN];
    const float4* hr = reinterpret_cast<const float4*>(h + (long long)node * HIDDEN);
#pragma unroll
    for (int q = 0; q < HIDDEN / 4; ++q) {
        float4 v = hr[q];
        hv[q * 4 + 0] = v.x; hv[q * 4 + 1] = v.y;
        hv[q * 4 + 2] = v.z; hv[q * 4 + 3] = v.w;
    }
    float z[N_CLASS];
#pragma unroll
    for (int c = 0; c < N_CLASS; ++c) z[c] = sb[c];
#pragma unroll
    for (int k = 0; k < HIDDEN; ++k) {
        float hk = hv[k];
#pragma unroll
        for (int c = 0; c < N_CLASS; ++c) z[c] += hk * sW[k * N_CLASS + c];
    }
    float m = z[0];
#pragma unroll
    for (int c = 1; c < N_CLASS; ++c) m = fmaxf(m, z[c]);
    float ssum = 0.0f;
#pragma unroll
    for (int c = 0; c < N_CLASS; ++c) ssum += expf(z[c] - m);
    float l = m + logf(ssum);
    float* orow = out + (long long)node * N_CLASS;
#pragma unroll
    for (int c = 0; c < N_CLASS; ++c) orow[c] = z[c] - l;
}

static inline char* align256(char* p) {
    return (char*)(((size_t)p + 255) & ~(size_t)255);
}

extern "C" void kernel_launch(void* const* d_in, const int* in_sizes, int n_in,
                              void* d_out, int out_size, void* d_ws, size_t ws_size,
                              hipStream_t stream) {
    const float* x   = (const float*)d_in[0];
    const int*   ei  = (const int*)d_in[1];
    const float* W1  = (const float*)d_in[2];
    const float* b1  = (const float*)d_in[3];
    const float* Wc0 = (const float*)d_in[4];
    const float* bc0 = (const float*)d_in[5];
    const float* Wc1 = (const float*)d_in[6];
    const float* bc1 = (const float*)d_in[7];
    const float* W2  = (const float*)d_in[8];
    const float* b2  = (const float*)d_in[9];
    float* out = (float*)d_out;

    long long E = (long long)in_sizes[1] / 2;

    char* p = (char*)d_ws;
    int* flag      = (int*)p;            p = align256(p + sizeof(int));
    int* cnt       = (int*)p;            p = align256(p + sizeof(int) * N_NODES);
    float* dinv    = (float*)p;          p = align256(p + sizeof(float) * N_NODES);
    int* bcnt      = (int*)p;            p = align256(p + sizeof(int) * NBKT);
    int* bkt_base  = (int*)p;            p = align256(p + sizeof(int) * (NBKT + 1));
    int* gcur      = (int*)p;            p = align256(p + sizeof(int) * NBKT);
    int* pairs     = (int*)p;            p = align256(p + sizeof(int) * E);
    float* h       = (float*)p;          p = align256(p + sizeof(float) * (size_t)N_NODES * HIDDEN);
    float* tmpp    = (float*)p;          p = align256(p + sizeof(float) * (size_t)N_NODES * HIDDEN);

    const int nblk_node   = (N_NODES + 255) / 256;
    const int nblk_edge   = (int)((E + 255) / 256);
    const int nblk_bucket = (int)((E + TILE - 1) / TILE);
    const int nblk_bcnt   = (NBKT + 255) / 256;

    hipMemsetAsync(cnt, 0, sizeof(int) * N_NODES, stream);
    k_detect<<<1, 1, 0, stream>>>(ei, flag);
    k_hist<<<nblk_edge, 256, 0, stream>>>(ei, E, flag, cnt);
    k_dinv<<<nblk_node, 256, 0, stream>>>(cnt, dinv);

    k_bktcnt<<<nblk_bcnt, 256, 0, stream>>>(cnt, bcnt);
    k_bktscan<<<1, 1024, 0, stream>>>(bcnt, gcur, bkt_base);
    k_bucket<<<nblk_bucket, 256, 0, stream>>>(ei, E, flag, gcur, pairs);

    k_lin1<<<nblk_node, 256, 0, stream>>>(x, W1, b1, h);

    // conv 1
    k_mm16<<<nblk_node, 256, 0, stream>>>(h, Wc0, dinv, tmpp);
    k_aggr<<<NBKT, 512, 0, stream>>>(bkt_base, pairs, tmpp, dinv, bc0, h);

    // conv 2
    k_mm16<<<nblk_node, 256, 0, stream>>>(h, Wc1, dinv, tmpp);
    k_aggr<<<NBKT, 512, 0, stream>>>(bkt_base, pairs, tmpp, dinv, bc1, h);

    k_out<<<nblk_node, 256, 0, stream>>>(h, W2, b2, out);
}